// Round 1
// 893.098 us; speedup vs baseline: 1.0874x; 1.0874x over previous
//
#include <hip/hip_runtime.h>
#include <hip/hip_bf16.h>
#include <cstdint>

typedef __hip_bfloat16 bf16;
typedef __attribute__((ext_vector_type(8))) short s8v;
typedef __attribute__((ext_vector_type(4))) float f32x4;

#define MFMA_BF16(a,b,c) __builtin_amdgcn_mfma_f32_16x16x32_bf16((a),(b),(c),0,0,0)

__device__ __forceinline__ float bf2f(bf16 v) { return __bfloat162float(v); }
__device__ __forceinline__ bf16 f2bf(float v) { return __float2bfloat16(v); }
__device__ __forceinline__ short f2bfbits(float v) {
  bf16 b = __float2bfloat16(v);
  short s; __builtin_memcpy(&s, &b, 2); return s;
}
__device__ __forceinline__ void g2lds16(const void* g, void* l) {
  __builtin_amdgcn_global_load_lds((__attribute__((address_space(1))) void*)(g),
                                   (__attribute__((address_space(3))) void*)(l), 16, 0, 0);
}
// unpack 8 contiguous bf16 (16B aligned) to f32
__device__ __forceinline__ void load8(const bf16* p, float v[8]) {
  uint4 r = *reinterpret_cast<const uint4*>(p);
  v[0]=__uint_as_float(r.x<<16); v[1]=__uint_as_float(r.x&0xffff0000u);
  v[2]=__uint_as_float(r.y<<16); v[3]=__uint_as_float(r.y&0xffff0000u);
  v[4]=__uint_as_float(r.z<<16); v[5]=__uint_as_float(r.z&0xffff0000u);
  v[6]=__uint_as_float(r.w<<16); v[7]=__uint_as_float(r.w&0xffff0000u);
}
// 8 contiguous f32 (16B aligned)
__device__ __forceinline__ void loadf8(const float* p, float v[8]) {
  float4 a = *(const float4*)p, b = *(const float4*)(p + 4);
  v[0]=a.x; v[1]=a.y; v[2]=a.z; v[3]=a.w;
  v[4]=b.x; v[5]=b.y; v[6]=b.z; v[7]=b.w;
}
// 8 contiguous f32 -> 8 bf16 (RNE)
__device__ __forceinline__ s8v cvt8(const float* p) {
  float4 a = *(const float4*)p, b = *(const float4*)(p + 4);
  s8v r;
  r[0]=f2bfbits(a.x); r[1]=f2bfbits(a.y); r[2]=f2bfbits(a.z); r[3]=f2bfbits(a.w);
  r[4]=f2bfbits(b.x); r[5]=f2bfbits(b.y); r[6]=f2bfbits(b.z); r[7]=f2bfbits(b.w);
  return r;
}

// ---------------- weight f32 -> bf16 convert (memory-bound) ----------------
__global__ __launch_bounds__(256) void ndt_cvt(
    const float* __restrict__ s, bf16* __restrict__ d, long n) {
  long i = ((long)blockIdx.x * 256 + threadIdx.x) * 8;
  if (i >= n) return;
  *(s8v*)(d + i) = cvt8(s + i);
}

// ---------------- K0: adaLN modulation (all f32) ---------------------------
__global__ __launch_bounds__(256) void ndt_ada(
    const float* __restrict__ c, const float* __restrict__ w_ada,
    const float* __restrict__ b_ada, float* __restrict__ mods) {
  const int wave = threadIdx.x >> 6, lane = threadIdx.x & 63;
  const int out = blockIdx.x * 4 + wave;          // 0..8191
  const float4* wrow = (const float4*)(w_ada + (long)out * 2048);
  const float4* c4 = (const float4*)c;
  float acc = 0.f;
  for (int k = lane; k < 512; k += 64) {
    float4 wv = wrow[k];
    float4 cv = c4[k];
    acc += (cv.x / (1.f + __expf(-cv.x))) * wv.x;
    acc += (cv.y / (1.f + __expf(-cv.y))) * wv.y;
    acc += (cv.z / (1.f + __expf(-cv.z))) * wv.z;
    acc += (cv.w / (1.f + __expf(-cv.w))) * wv.w;
  }
  #pragma unroll
  for (int o = 32; o; o >>= 1) acc += __shfl_xor(acc, o, 64);
  if (lane == 0) {
    float m = acc + b_ada[out];
    int grp = out >> 11, idx = out & 2047;
    mods[grp * 2048 + idx] = (grp & 1) ? tanhf(m) : (1.f + m);
  }
}

// ---------------- K1: h1 = rmsnorm(x)*w*(1+s_msa), f32 in -> bf16 out ------
__global__ __launch_bounds__(256) void ndt_norm_mod(
    const float* __restrict__ x, const float* __restrict__ w,
    const float* __restrict__ smod, bf16* __restrict__ out) {
  const int t = blockIdx.x, tid = threadIdx.x;
  __shared__ float red[4];
  float v[8];
  loadf8(x + (long)t * 2048 + tid * 8, v);
  float ss = 0.f;
  #pragma unroll
  for (int i = 0; i < 8; i++) ss += v[i] * v[i];
  #pragma unroll
  for (int o = 32; o; o >>= 1) ss += __shfl_xor(ss, o, 64);
  if ((tid & 63) == 0) red[tid >> 6] = ss;
  __syncthreads();
  float r = rsqrtf((red[0]+red[1]+red[2]+red[3]) * (1.f/2048.f) + 1e-5f);
  #pragma unroll
  for (int i = 0; i < 8; i++) {
    int cc = tid * 8 + i;
    out[(long)t * 2048 + cc] = f2bf(v[i] * r * w[cc] * smod[cc]);
  }
}

// ------- GEMM (fast path): C = A(bf16,MxK) * B(bf16,NxK)^T, m97 staging ----
// EPI: 0 plain, 1 silu, 2 *aux
template<int EPI>
__global__ __launch_bounds__(256) void ndt_gemm_bb(
    const bf16* __restrict__ A, const bf16* __restrict__ B,
    bf16* __restrict__ C, const bf16* __restrict__ aux,
    int M, int N, int K) {
  __shared__ alignas(16) short sA[128 * 32];
  __shared__ alignas(16) short sB[128 * 32];
  const int tid = threadIdx.x;
  const int wave = tid >> 6, lane = tid & 63;
  const int quad = lane >> 4, l15 = lane & 15;
  const int wm = (wave >> 1) << 6, wn = (wave & 1) << 6;
  const long m0 = (long)blockIdx.x * 128, n0 = (long)blockIdx.y * 128;
  f32x4 zero4 = {0.f, 0.f, 0.f, 0.f};
  f32x4 acc[4][4];
  #pragma unroll
  for (int i = 0; i < 4; i++)
    #pragma unroll
    for (int j = 0; j < 4; j++) acc[i][j] = zero4;
  const int srow = lane >> 2;          // 0..15 within 16-row segment
  const int skc  = (lane & 3) * 8;     // k-chunk of 8 bf16
  for (int k0 = 0; k0 < K; k0 += 32) {
    #pragma unroll
    for (int it = 0; it < 2; it++) {
      int seg = wave * 2 + it;         // 0..7, 16 rows each
      int row = seg * 16 + srow;
      g2lds16(A + (m0 + row) * (long)K + k0 + skc, (char*)sA + seg * 1024);
      g2lds16(B + (n0 + row) * (long)K + k0 + skc, (char*)sB + seg * 1024);
    }
    __syncthreads();
    s8v af[4], bfr[4];
    #pragma unroll
    for (int i = 0; i < 4; i++) af[i]  = *(const s8v*)&sA[(wm + i*16 + l15)*32 + quad*8];
    #pragma unroll
    for (int j = 0; j < 4; j++) bfr[j] = *(const s8v*)&sB[(wn + j*16 + l15)*32 + quad*8];
    #pragma unroll
    for (int i = 0; i < 4; i++)
      #pragma unroll
      for (int j = 0; j < 4; j++)
        acc[i][j] = MFMA_BF16(af[i], bfr[j], acc[i][j]);
    __syncthreads();
  }
  #pragma unroll
  for (int i = 0; i < 4; i++) {
    long rg = m0 + wm + i*16 + quad*4;
    #pragma unroll
    for (int j = 0; j < 4; j++) {
      long cg = n0 + wn + j*16 + l15;
      #pragma unroll
      for (int r = 0; r < 4; r++) {
        float v = acc[i][j][r];
        long idx = (rg + r) * (long)N + cg;
        if (EPI == 1) v = v / (1.f + __expf(-v));
        if (EPI == 2) v = v * bf2f(aux[idx]);
        C[idx] = f2bf(v);
      }
    }
  }
}

// ======= GEMM8: 256x256 tile, BK=64, 8 waves, 8-phase counted-vmcnt ========
// T1 (XCD swizzle) + T2 (st_16x32 LDS swizzle, linear-dest/inv-swz-source)
// + T3/T4 (8-phase, vmcnt(6) at phases 4/8 only) + T5 (setprio around MFMA).
// Requires: M%256==0, N%256==0, K%128==0. grid = dim3(M/256, N/256), 512 thr.
//
// LDS layout per tile: [256 rows][64 k] bf16, 128B rows, 32KB; swizzle
// byte ^= ((byte>>9)&1)<<5 applied identically on stage-source and ds_read.
__device__ __forceinline__ void stage64(const bf16* __restrict__ G, long g0,
                                        int K, int t, char* tile, int q, int tid) {
  // stage rows [q*64, q*64+64) of the k-tile t: 512 thr x 16B = 8KB, linear dest
  int L = q * 8192 + tid * 16;              // linear byte offset within 32KB tile
  int Ls = L ^ (((L >> 9) & 1) << 5);       // inverse-swizzled source offset
  const char* src = (const char*)(G + (g0 + (Ls >> 7)) * (long)K + t * 64) + (Ls & 127);
  g2lds16(src, tile + L);
}

__device__ __forceinline__ void phase_bar() {
  asm volatile("" ::: "memory");
  __builtin_amdgcn_s_barrier();
  asm volatile("" ::: "memory");
}

#define READ_A8(tA, h) do { \
  _Pragma("unroll") for (int i_ = 0; i_ < 4; i_++) { \
    int row_ = wm * 128 + (h) * 64 + i_ * 16 + l15; \
    _Pragma("unroll") for (int kk_ = 0; kk_ < 2; kk_++) { \
      int P_ = row_ * 128 + kk_ * 64 + quad * 16; \
      af[kk_][i_] = *(const s8v*)((tA) + (P_ ^ (((P_ >> 9) & 1) << 5))); } } } while (0)

#define READ_B8(tB, nh, bfreg) do { \
  _Pragma("unroll") for (int j_ = 0; j_ < 2; j_++) { \
    int col_ = wn * 64 + (nh) * 32 + j_ * 16 + l15; \
    _Pragma("unroll") for (int kk_ = 0; kk_ < 2; kk_++) { \
      int P_ = col_ * 128 + kk_ * 64 + quad * 16; \
      bfreg[kk_][j_] = *(const s8v*)((tB) + (P_ ^ (((P_ >> 9) & 1) << 5))); } } } while (0)

#define MMQ8(h, nh, bfreg) do { \
  __builtin_amdgcn_s_setprio(1); \
  _Pragma("unroll") for (int i_ = 0; i_ < 4; i_++) \
    _Pragma("unroll") for (int j_ = 0; j_ < 2; j_++) { \
      acc[(h)*4 + i_][(nh)*2 + j_] = MFMA_BF16(af[0][i_], bfreg[0][j_], acc[(h)*4 + i_][(nh)*2 + j_]); \
      acc[(h)*4 + i_][(nh)*2 + j_] = MFMA_BF16(af[1][i_], bfreg[1][j_], acc[(h)*4 + i_][(nh)*2 + j_]); } \
  __builtin_amdgcn_s_setprio(0); } while (0)

template<int EPI>
__global__ __launch_bounds__(512, 2) void ndt_gemm8(
    const bf16* __restrict__ A, const bf16* __restrict__ B,
    bf16* __restrict__ C, const bf16* __restrict__ aux,
    int M, int N, int K) {
  __shared__ alignas(16) short lds8[65536];   // 128 KiB: [A0|B0|A1|B1] 32KB each
  char* const tA0 = (char*)lds8;
  char* const tB0 = tA0 + 32768;
  char* const tA1 = tA0 + 65536;
  char* const tB1 = tA0 + 98304;

  const int tid = threadIdx.x;
  const int wid = tid >> 6, lane = tid & 63;
  const int quad = lane >> 4, l15 = lane & 15;
  const int wm = wid >> 2, wn = wid & 3;      // 2x4 wave grid, 128x64 per wave

  // T1: bijective XCD-aware block swizzle (nwg multiple of 8 here)
  const int nbx = gridDim.x;
  int bid = blockIdx.y * nbx + blockIdx.x;
  const int nwg = nbx * (int)gridDim.y;
  if ((nwg & 7) == 0) bid = (bid & 7) * (nwg >> 3) + (bid >> 3);
  const long m0 = (long)(bid % nbx) * 256;
  const long n0 = (long)(bid / nbx) * 256;

  const int NT = K >> 6;        // 64-wide k-tiles (even, >=2)
  const int NI = NT >> 1;

  f32x4 acc[8][4];
  f32x4 zero4 = {0.f, 0.f, 0.f, 0.f};
  #pragma unroll
  for (int i = 0; i < 8; i++)
    #pragma unroll
    for (int j = 0; j < 4; j++) acc[i][j] = zero4;

  s8v af[2][4], bf0[2][2], bf1[2][2];

  // ---- prologue: tile0 full (8 loads), tile1 A full + B-h0 (6 loads) ----
  #pragma unroll
  for (int q = 0; q < 4; q++) stage64(A, m0, K, 0, tA0, q, tid);
  #pragma unroll
  for (int q = 0; q < 4; q++) stage64(B, n0, K, 0, tB0, q, tid);
  #pragma unroll
  for (int q = 0; q < 4; q++) stage64(A, m0, K, 1, tA1, q, tid);
  stage64(B, n0, K, 1, tB1, 0, tid);
  stage64(B, n0, K, 1, tB1, 1, tid);
  asm volatile("s_waitcnt vmcnt(6)" ::: "memory");  // tile0 landed
  phase_bar();

  for (int it = 0; it < NI; ++it) {
    const int T = 2 * it;
    const int t2 = (T + 2 < NT) ? T + 2 : NT - 1;   // clamped prefetch (safe:
    const int t3 = (T + 3 < NT) ? T + 3 : NT - 1;   // targets already-consumed)
    // ---- K-tile T (buf0) ----
    // ph1: compute (M0,N0); stage B-h1 of T+1 -> buf1
    READ_A8(tA0, 0);
    READ_B8(tB0, 0, bf0);
    stage64(B, n0, K, T + 1, tB1, 2, tid);
    stage64(B, n0, K, T + 1, tB1, 3, tid);
    phase_bar(); MMQ8(0, 0, bf0); phase_bar();
    // ph2: compute (M0,N1); stage A q0,q2 of T+2 -> buf0
    READ_B8(tB0, 1, bf1);
    stage64(A, m0, K, t2, tA0, 0, tid);
    stage64(A, m0, K, t2, tA0, 2, tid);
    phase_bar(); MMQ8(0, 1, bf1); phase_bar();
    // ph3: compute (M1,N0); stage B-h0 of T+2 -> buf0
    READ_A8(tA0, 1);
    stage64(B, n0, K, t2, tB0, 0, tid);
    stage64(B, n0, K, t2, tB0, 1, tid);
    phase_bar(); MMQ8(1, 0, bf0); phase_bar();
    // ph4: compute (M1,N1); stage A q1,q3 of T+2 -> buf0; drain to 6
    stage64(A, m0, K, t2, tA0, 1, tid);
    stage64(A, m0, K, t2, tA0, 3, tid);
    asm volatile("s_waitcnt vmcnt(6)" ::: "memory");  // tile T+1 landed
    phase_bar(); MMQ8(1, 1, bf1); phase_bar();
    // ---- K-tile T+1 (buf1) ----
    // ph5: stage B-h1 of T+2 -> buf0
    READ_A8(tA1, 0);
    READ_B8(tB1, 0, bf0);
    stage64(B, n0, K, t2, tB0, 2, tid);
    stage64(B, n0, K, t2, tB0, 3, tid);
    phase_bar(); MMQ8(0, 0, bf0); phase_bar();
    // ph6: stage A q0,q2 of T+3 -> buf1
    READ_B8(tB1, 1, bf1);
    stage64(A, m0, K, t3, tA1, 0, tid);
    stage64(A, m0, K, t3, tA1, 2, tid);
    phase_bar(); MMQ8(0, 1, bf1); phase_bar();
    // ph7: stage B-h0 of T+3 -> buf1
    READ_A8(tA1, 1);
    stage64(B, n0, K, t3, tB1, 0, tid);
    stage64(B, n0, K, t3, tB1, 1, tid);
    phase_bar(); MMQ8(1, 0, bf0); phase_bar();
    // ph8: stage A q1,q3 of T+3 -> buf1; drain to 6
    stage64(A, m0, K, t3, tA1, 1, tid);
    stage64(A, m0, K, t3, tA1, 3, tid);
    asm volatile("s_waitcnt vmcnt(6)" ::: "memory");  // tile T+2 landed
    phase_bar(); MMQ8(1, 1, bf1); phase_bar();
  }
  asm volatile("s_waitcnt vmcnt(0)" ::: "memory");    // drain stray prefetches

  #pragma unroll
  for (int mi = 0; mi < 8; mi++) {
    long rg = m0 + wm * 128 + mi * 16 + quad * 4;
    #pragma unroll
    for (int nj = 0; nj < 4; nj++) {
      long cg = n0 + wn * 64 + nj * 16 + l15;
      #pragma unroll
      for (int r = 0; r < 4; r++) {
        float v = acc[mi][nj][r];
        long idx = (rg + r) * (long)N + cg;
        if (EPI == 1) v = v / (1.f + __expf(-v));
        if (EPI == 2) v = v * bf2f(aux[idx]);
        C[idx] = f2bf(v);
      }
    }
  }
}

// ------- GEMM (fallback): B is f32, converted during explicit staging ------
template<int EPI>
__global__ __launch_bounds__(256) void ndt_gemm_bt(
    const bf16* __restrict__ A, const float* __restrict__ B,
    bf16* __restrict__ C, const bf16* __restrict__ aux,
    int M, int N, int K) {
  __shared__ alignas(16) short sA[128 * 32];
  __shared__ alignas(16) short sB[128 * 32];
  const int tid = threadIdx.x;
  const int wave = tid >> 6, lane = tid & 63;
  const int quad = lane >> 4, l15 = lane & 15;
  const int wm = (wave >> 1) << 6, wn = (wave & 1) << 6;
  const long m0 = (long)blockIdx.x * 128, n0 = (long)blockIdx.y * 128;
  f32x4 zero4 = {0.f, 0.f, 0.f, 0.f};
  f32x4 acc[4][4];
  #pragma unroll
  for (int i = 0; i < 4; i++)
    #pragma unroll
    for (int j = 0; j < 4; j++) acc[i][j] = zero4;
  const int srow = lane >> 2;
  const int skc  = (lane & 3) * 8;
  const int r0 = (wave * 2) * 16 + srow;
  const int r1 = (wave * 2 + 1) * 16 + srow;
  const bf16*  pa0 = A + (m0 + r0) * (long)K + skc;
  const bf16*  pa1 = A + (m0 + r1) * (long)K + skc;
  const float* pb0 = B + (n0 + r0) * (long)K + skc;
  const float* pb1 = B + (n0 + r1) * (long)K + skc;
  uint4* da0 = (uint4*)&sA[r0 * 32 + skc];
  uint4* da1 = (uint4*)&sA[r1 * 32 + skc];
  s8v* db0 = (s8v*)&sB[r0 * 32 + skc];
  s8v* db1 = (s8v*)&sB[r1 * 32 + skc];
  for (int k0 = 0; k0 < K; k0 += 32) {
    uint4 va0 = *(const uint4*)pa0; pa0 += 32;
    uint4 va1 = *(const uint4*)pa1; pa1 += 32;
    s8v vb0 = cvt8(pb0); pb0 += 32;
    s8v vb1 = cvt8(pb1); pb1 += 32;
    *da0 = va0; *da1 = va1; *db0 = vb0; *db1 = vb1;
    __syncthreads();
    s8v af[4], bfr[4];
    #pragma unroll
    for (int i = 0; i < 4; i++) af[i]  = *(const s8v*)&sA[(wm + i*16 + l15)*32 + quad*8];
    #pragma unroll
    for (int j = 0; j < 4; j++) bfr[j] = *(const s8v*)&sB[(wn + j*16 + l15)*32 + quad*8];
    #pragma unroll
    for (int i = 0; i < 4; i++)
      #pragma unroll
      for (int j = 0; j < 4; j++)
        acc[i][j] = MFMA_BF16(af[i], bfr[j], acc[i][j]);
    __syncthreads();
  }
  #pragma unroll
  for (int i = 0; i < 4; i++) {
    long rg = m0 + wm + i*16 + quad*4;
    #pragma unroll
    for (int j = 0; j < 4; j++) {
      long cg = n0 + wn + j*16 + l15;
      #pragma unroll
      for (int r = 0; r < 4; r++) {
        float v = acc[i][j][r];
        long idx = (rg + r) * (long)N + cg;
        if (EPI == 1) v = v / (1.f + __expf(-v));
        if (EPI == 2) v = v * bf2f(aux[idx]);
        C[idx] = f2bf(v);
      }
    }
  }
}

// ---------------- K3: q/k rmsnorm + RoPE, v copy ---------------------------
__global__ __launch_bounds__(256) void ndt_qkrope(
    const bf16* __restrict__ qkv, const float* __restrict__ qw, const float* __restrict__ kw,
    const float* __restrict__ fc, const float* __restrict__ fs,
    bf16* __restrict__ qb, bf16* __restrict__ kb, bf16* __restrict__ vb) {
  const int wid = blockIdx.x * 4 + (threadIdx.x >> 6);
  const int lane = threadIdx.x & 63;
  const int t = wid / 48;
  const int u = wid - t * 48;
  if (u < 40) {
    const bool isq = (u < 32);
    const int hh = isq ? u : (u - 32);
    const long src = (long)t * 3072 + (isq ? hh * 64 : 2048 + hh * 64) + lane;
    float v = bf2f(qkv[src]);
    float ss = v * v;
    #pragma unroll
    for (int o = 32; o; o >>= 1) ss += __shfl_xor(ss, o, 64);
    float r = rsqrtf(ss * (1.f/64.f) + 1e-5f);
    float y = v * r * (isq ? qw[lane] : kw[lane]);
    int j = lane >> 1;
    float cv = fc[t * 32 + j];
    float sv = fs[t * 32 + j];
    float p = __shfl_xor(y, 1, 64);
    float out = (lane & 1) ? (p * sv + y * cv) : (y * cv - p * sv);
    if (isq) qb[(long)t * 2048 + hh * 64 + lane] = f2bf(out);
    else     kb[(long)t * 512 + hh * 64 + lane] = f2bf(out);
  } else {
    const int vh = u - 40;
    vb[(long)t * 512 + vh * 64 + lane] = qkv[(long)t * 3072 + 2560 + vh * 64 + lane];
  }
}

// ---------------- K4: flash attention (GQA 32 q-heads / 8 kv-heads) --------
__global__ __launch_bounds__(256) void ndt_attn(
    const bf16* __restrict__ qb, const bf16* __restrict__ kb,
    const bf16* __restrict__ vb, bf16* __restrict__ ob) {
  const int h = blockIdx.y;
  const int qblk = blockIdx.x;
  const int tid = threadIdx.x;
  const int wave = tid >> 6, lane = tid & 63;
  const int quad = lane >> 4, l15 = lane & 15;
  const int kh = h >> 2;
  __shared__ alignas(16) short kT[64 * 72];     // [key][d], padded
  __shared__ alignas(16) short vT[64 * 72];     // [d][key], padded
  __shared__ alignas(16) short pT[4][16 * 72];  // per-wave P, [qrow][key]
  const int qrow = qblk * 64 + wave * 16 + l15;
  const short* qptr = (const short*)qb + (long)qrow * 2048 + h * 64;
  s8v qf0 = *(const s8v*)(qptr + quad * 8);
  s8v qf1 = *(const s8v*)(qptr + 32 + quad * 8);
  f32x4 zero4 = {0.f, 0.f, 0.f, 0.f};
  f32x4 o[4];
  float mr[4], lr[4];
  #pragma unroll
  for (int r = 0; r < 4; r++) { o[r] = zero4; mr[r] = -1e30f; lr[r] = 0.f; }
  const int skey = tid >> 2;          // 0..63
  const int sdg = (tid & 3) * 16;     // 0,16,32,48
  for (int kt = 0; kt < 32; kt++) {
    {
      const short* ksrc = (const short*)kb + ((long)(kt * 64 + skey) * 8 + kh) * 64 + sdg;
      *(uint4*)&kT[skey * 72 + sdg]     = *(const uint4*)(ksrc);
      *(uint4*)&kT[skey * 72 + sdg + 8] = *(const uint4*)(ksrc + 8);
      const short* vsrc = (const short*)vb + ((long)(kt * 64 + skey) * 8 + kh) * 64 + sdg;
      short tv[16];
      *(uint4*)&tv[0] = *(const uint4*)(vsrc);
      *(uint4*)&tv[8] = *(const uint4*)(vsrc + 8);
      #pragma unroll
      for (int i = 0; i < 16; i++) vT[(sdg + i) * 72 + skey] = tv[i];
    }
    __syncthreads();
    f32x4 s[4];
    #pragma unroll
    for (int b4 = 0; b4 < 4; b4++) {
      const short* kr = &kT[(b4 * 16 + l15) * 72];
      s8v kf0 = *(const s8v*)(kr + quad * 8);
      s8v kf1 = *(const s8v*)(kr + 32 + quad * 8);
      f32x4 z = zero4;
      z = MFMA_BF16(qf0, kf0, z);
      z = MFMA_BF16(qf1, kf1, z);
      s[b4] = z;
    }
    #pragma unroll
    for (int r = 0; r < 4; r++) {
      float mx = -1e30f;
      #pragma unroll
      for (int b4 = 0; b4 < 4; b4++) { float sv2 = s[b4][r] * 0.125f; s[b4][r] = sv2; mx = fmaxf(mx, sv2); }
      mx = fmaxf(mx, __shfl_xor(mx, 1, 64));
      mx = fmaxf(mx, __shfl_xor(mx, 2, 64));
      mx = fmaxf(mx, __shfl_xor(mx, 4, 64));
      mx = fmaxf(mx, __shfl_xor(mx, 8, 64));
      float nm = fmaxf(mr[r], mx);
      float alpha = __expf(mr[r] - nm);
      mr[r] = nm;
      float rs = 0.f;
      #pragma unroll
      for (int b4 = 0; b4 < 4; b4++) { float p = __expf(s[b4][r] - nm); s[b4][r] = p; rs += p; }
      rs += __shfl_xor(rs, 1, 64);
      rs += __shfl_xor(rs, 2, 64);
      rs += __shfl_xor(rs, 4, 64);
      rs += __shfl_xor(rs, 8, 64);
      lr[r] = lr[r] * alpha + rs;
      #pragma unroll
      for (int cb = 0; cb < 4; cb++) o[cb][r] *= alpha;
    }
    short* pw = &pT[wave][0];
    #pragma unroll
    for (int b4 = 0; b4 < 4; b4++)
      #pragma unroll
      for (int r = 0; r < 4; r++)
        pw[(quad * 4 + r) * 72 + b4 * 16 + l15] = f2bfbits(s[b4][r]);
    const short* pr = &pT[wave][0];
    s8v pf0 = *(const s8v*)(pr + l15 * 72 + quad * 8);
    s8v pf1 = *(const s8v*)(pr + l15 * 72 + 32 + quad * 8);
    #pragma unroll
    for (int cb = 0; cb < 4; cb++) {
      const short* vr = &vT[(cb * 16 + l15) * 72];
      s8v vf0 = *(const s8v*)(vr + quad * 8);
      s8v vf1 = *(const s8v*)(vr + 32 + quad * 8);
      o[cb] = MFMA_BF16(pf0, vf0, o[cb]);
      o[cb] = MFMA_BF16(pf1, vf1, o[cb]);
    }
    __syncthreads();
  }
  #pragma unroll
  for (int cb = 0; cb < 4; cb++)
    #pragma unroll
    for (int r = 0; r < 4; r++) {
      int tok = qblk * 64 + wave * 16 + quad * 4 + r;
      ob[(long)tok * 2048 + h * 64 + cb * 16 + l15] = f2bf(o[cb][r] / lr[r]);
    }
}

// ---- K6: x1(f32) = x + g_msa*rms(ao)*w_n2 ; h2(bf16) = rms(x1)*w_f1*s_mlp --
__global__ __launch_bounds__(256) void ndt_resid1(
    const float* __restrict__ x, const bf16* __restrict__ ao,
    const float* __restrict__ mods, const float* __restrict__ w_n2,
    const float* __restrict__ w_f1, float* __restrict__ x1, bf16* __restrict__ h2) {
  const int t = blockIdx.x, tid = threadIdx.x;
  __shared__ float red1[4], red2[4];
  const long base = (long)t * 2048;
  float a[8], xv[8], y[8];
  load8(ao + base + tid * 8, a);
  loadf8(x + base + tid * 8, xv);
  float ss = 0.f;
  #pragma unroll
  for (int i = 0; i < 8; i++) ss += a[i] * a[i];
  #pragma unroll
  for (int o = 32; o; o >>= 1) ss += __shfl_xor(ss, o, 64);
  if ((tid & 63) == 0) red1[tid >> 6] = ss;
  __syncthreads();
  float r1 = rsqrtf((red1[0]+red1[1]+red1[2]+red1[3]) * (1.f/2048.f) + 1e-5f);
  float ss2 = 0.f;
  #pragma unroll
  for (int i = 0; i < 8; i++) {
    int cc = tid * 8 + i;
    float yy = xv[i] + mods[2048 + cc] * (a[i] * r1 * w_n2[cc]);
    y[i] = yy; ss2 += yy * yy;
    x1[base + cc] = yy;
  }
  #pragma unroll
  for (int o = 32; o; o >>= 1) ss2 += __shfl_xor(ss2, o, 64);
  if ((tid & 63) == 0) red2[tid >> 6] = ss2;
  __syncthreads();
  float r2 = rsqrtf((red2[0]+red2[1]+red2[2]+red2[3]) * (1.f/2048.f) + 1e-5f);
  #pragma unroll
  for (int i = 0; i < 8; i++) {
    int cc = tid * 8 + i;
    h2[base + cc] = f2bf(y[i] * r2 * w_f1[cc] * mods[4096 + cc]);
  }
}

// ---------------- K10: out(f32) = x1 + g_mlp*rms(ffn)*w_f2 -----------------
__global__ __launch_bounds__(256) void ndt_resid2(
    const float* __restrict__ x1, const bf16* __restrict__ ffn,
    const float* __restrict__ mods, const float* __restrict__ w_f2,
    float* __restrict__ out) {
  const int t = blockIdx.x, tid = threadIdx.x;
  __shared__ float red[4];
  const long base = (long)t * 2048;
  float f[8], xv[8];
  load8(ffn + base + tid * 8, f);
  loadf8(x1 + base + tid * 8, xv);
  float ss = 0.f;
  #pragma unroll
  for (int i = 0; i < 8; i++) ss += f[i] * f[i];
  #pragma unroll
  for (int o = 32; o; o >>= 1) ss += __shfl_xor(ss, o, 64);
  if ((tid & 63) == 0) red[tid >> 6] = ss;
  __syncthreads();
  float r = rsqrtf((red[0]+red[1]+red[2]+red[3]) * (1.f/2048.f) + 1e-5f);
  #pragma unroll
  for (int i = 0; i < 8; i++) {
    int cc = tid * 8 + i;
    out[base + cc] = xv[i] + mods[6144 + cc] * (f[i] * r * w_f2[cc]);
  }
}

// ---------------------------------------------------------------------------
extern "C" void kernel_launch(void* const* d_in, const int* in_sizes, int n_in,
                              void* d_out, int out_size, void* d_ws, size_t ws_size,
                              hipStream_t stream) {
  const float* x     = (const float*)d_in[0];
  const float* fc    = (const float*)d_in[2];
  const float* fs    = (const float*)d_in[3];
  const float* c     = (const float*)d_in[4];
  const float* w_qkv = (const float*)d_in[5];
  const float* w_out = (const float*)d_in[6];
  const float* q_nw  = (const float*)d_in[7];
  const float* k_nw  = (const float*)d_in[8];
  const float* an1   = (const float*)d_in[9];
  const float* an2   = (const float*)d_in[10];
  const float* fn1   = (const float*)d_in[11];
  const float* fn2   = (const float*)d_in[12];
  const float* w1    = (const float*)d_in[13];
  const float* w2    = (const float*)d_in[14];
  const float* w3    = (const float*)d_in[15];
  const float* w_ada = (const float*)d_in[16];
  const float* b_ada = (const float*)d_in[17];
  float* out = (float*)d_out;

  const size_t MB = 1024 * 1024;
  char* w = (char*)d_ws;
  float* mods = (float*)(w);                    // 32 KB f32
  char* base = w + 32768;
  bf16* h1   = (bf16*)(base);                   // 8 MB bf16: h1 -> attn -> ffn
  bf16* attn = h1;
  bf16* ffn  = h1;
  bf16* qkv  = (bf16*)(base + 8 * MB);          // 12 MB bf16: qkv -> ao
  bf16* ao   = qkv;
  bf16* qb   = (bf16*)(base + 20 * MB);         // 8 MB bf16: qb -> h2
  bf16* h2   = qb;
  bf16* kb   = (bf16*)(base + 28 * MB);         // 2 MB bf16
  bf16* vb   = (bf16*)(base + 30 * MB);         // 2 MB bf16
  float* x1  = (float*)(base + 32 * MB);        // 16 MB f32
  bf16* t1   = (bf16*)(base + 48 * MB);         // 32 MB bf16
  // fast-path bf16 weight regions (lifetime-overlapped)
  bf16* Wa   = (bf16*)(base + 80 * MB);         // 32 MB
  bf16* Wb   = (bf16*)(base + 112 * MB);        // 32 MB
  const size_t needed = 32768 + 144 * MB;

  ndt_ada<<<2048, 256, 0, stream>>>(c, w_ada, b_ada, mods);
  ndt_norm_mod<<<2048, 256, 0, stream>>>(x, an1, mods, h1);

  if (ws_size >= needed) {
    // --- fast path: pre-convert weights to bf16; 8-phase 256^2 for FFN-up ---
    ndt_cvt<<<3072, 256, 0, stream>>>(w_qkv, Wa, 6291456L);
    ndt_gemm_bb<0><<<dim3(16, 24), 256, 0, stream>>>(h1, Wa, qkv, nullptr, 2048, 3072, 2048);
    ndt_qkrope<<<24576, 256, 0, stream>>>(qkv, q_nw, k_nw, fc, fs, qb, kb, vb);
    ndt_attn<<<dim3(32, 32), 256, 0, stream>>>(qb, kb, vb, attn);
    ndt_cvt<<<2048, 256, 0, stream>>>(w_out, Wa, 4194304L);
    ndt_gemm_bb<0><<<dim3(16, 16), 256, 0, stream>>>(attn, Wa, ao, nullptr, 2048, 2048, 2048);
    ndt_resid1<<<2048, 256, 0, stream>>>(x, ao, mods, an2, fn1, x1, h2);
    ndt_cvt<<<8192, 256, 0, stream>>>(w1, Wa, 16777216L);
    ndt_cvt<<<8192, 256, 0, stream>>>(w3, Wb, 16777216L);
    ndt_gemm8<1><<<dim3(8, 32), 512, 0, stream>>>(h2, Wa, t1, nullptr, 2048, 8192, 2048);
    ndt_gemm8<2><<<dim3(8, 32), 512, 0, stream>>>(h2, Wb, t1, t1, 2048, 8192, 2048);
    ndt_cvt<<<8192, 256, 0, stream>>>(w2, Wa, 16777216L);
    ndt_gemm_bb<0><<<dim3(16, 16), 256, 0, stream>>>(t1, Wa, ffn, nullptr, 2048, 2048, 8192);
  } else {
    // --- fallback: round-3 passing path (f32 B staged with in-loop cvt) ---
    ndt_gemm_bt<0><<<dim3(16, 24), 256, 0, stream>>>(h1, w_qkv, qkv, nullptr, 2048, 3072, 2048);
    ndt_qkrope<<<24576, 256, 0, stream>>>(qkv, q_nw, k_nw, fc, fs, qb, kb, vb);
    ndt_attn<<<dim3(32, 32), 256, 0, stream>>>(qb, kb, vb, attn);
    ndt_gemm_bt<0><<<dim3(16, 16), 256, 0, stream>>>(attn, w_out, ao, nullptr, 2048, 2048, 2048);
    ndt_resid1<<<2048, 256, 0, stream>>>(x, ao, mods, an2, fn1, x1, h2);
    ndt_gemm_bt<1><<<dim3(16, 64), 256, 0, stream>>>(h2, w1, t1, nullptr, 2048, 8192, 2048);
    ndt_gemm_bt<2><<<dim3(16, 64), 256, 0, stream>>>(h2, w3, t1, t1, 2048, 8192, 2048);
    ndt_gemm_bt<0><<<dim3(16, 16), 256, 0, stream>>>(t1, w2, ffn, nullptr, 2048, 2048, 8192);
  }
  ndt_resid2<<<2048, 256, 0, stream>>>(x1, ffn, mods, fn2, out);
}

// Round 2
// 778.483 us; speedup vs baseline: 1.2475x; 1.1472x over previous
//
#include <hip/hip_runtime.h>
#include <hip/hip_bf16.h>
#include <cstdint>

typedef __hip_bfloat16 bf16;
typedef __attribute__((ext_vector_type(8))) short s8v;
typedef __attribute__((ext_vector_type(4))) float f32x4;

#define MFMA_BF16(a,b,c) __builtin_amdgcn_mfma_f32_16x16x32_bf16((a),(b),(c),0,0,0)

__device__ __forceinline__ float bf2f(bf16 v) { return __bfloat162float(v); }
__device__ __forceinline__ bf16 f2bf(float v) { return __float2bfloat16(v); }
__device__ __forceinline__ short f2bfbits(float v) {
  bf16 b = __float2bfloat16(v);
  short s; __builtin_memcpy(&s, &b, 2); return s;
}
__device__ __forceinline__ void g2lds16(const void* g, void* l) {
  __builtin_amdgcn_global_load_lds((__attribute__((address_space(1))) void*)(g),
                                   (__attribute__((address_space(3))) void*)(l), 16, 0, 0);
}
__device__ __forceinline__ void load8(const bf16* p, float v[8]) {
  uint4 r = *reinterpret_cast<const uint4*>(p);
  v[0]=__uint_as_float(r.x<<16); v[1]=__uint_as_float(r.x&0xffff0000u);
  v[2]=__uint_as_float(r.y<<16); v[3]=__uint_as_float(r.y&0xffff0000u);
  v[4]=__uint_as_float(r.z<<16); v[5]=__uint_as_float(r.z&0xffff0000u);
  v[6]=__uint_as_float(r.w<<16); v[7]=__uint_as_float(r.w&0xffff0000u);
}
__device__ __forceinline__ void loadf8(const float* p, float v[8]) {
  float4 a = *(const float4*)p, b = *(const float4*)(p + 4);
  v[0]=a.x; v[1]=a.y; v[2]=a.z; v[3]=a.w;
  v[4]=b.x; v[5]=b.y; v[6]=b.z; v[7]=b.w;
}
__device__ __forceinline__ s8v cvt8(const float* p) {
  float4 a = *(const float4*)p, b = *(const float4*)(p + 4);
  s8v r;
  r[0]=f2bfbits(a.x); r[1]=f2bfbits(a.y); r[2]=f2bfbits(a.z); r[3]=f2bfbits(a.w);
  r[4]=f2bfbits(b.x); r[5]=f2bfbits(b.y); r[6]=f2bfbits(b.z); r[7]=f2bfbits(b.w);
  return r;
}

// ---------------- weight f32 -> bf16 convert (memory-bound) ----------------
__global__ __launch_bounds__(256) void ndt_cvt(
    const float* __restrict__ s, bf16* __restrict__ d, long n) {
  long i = ((long)blockIdx.x * 256 + threadIdx.x) * 8;
  if (i >= n) return;
  *(s8v*)(d + i) = cvt8(s + i);
}

// ---------------- K0: adaLN modulation (all f32) ---------------------------
__global__ __launch_bounds__(256) void ndt_ada(
    const float* __restrict__ c, const float* __restrict__ w_ada,
    const float* __restrict__ b_ada, float* __restrict__ mods) {
  const int wave = threadIdx.x >> 6, lane = threadIdx.x & 63;
  const int out = blockIdx.x * 4 + wave;          // 0..8191
  const float4* wrow = (const float4*)(w_ada + (long)out * 2048);
  const float4* c4 = (const float4*)c;
  float acc = 0.f;
  for (int k = lane; k < 512; k += 64) {
    float4 wv = wrow[k];
    float4 cv = c4[k];
    acc += (cv.x / (1.f + __expf(-cv.x))) * wv.x;
    acc += (cv.y / (1.f + __expf(-cv.y))) * wv.y;
    acc += (cv.z / (1.f + __expf(-cv.z))) * wv.z;
    acc += (cv.w / (1.f + __expf(-cv.w))) * wv.w;
  }
  #pragma unroll
  for (int o = 32; o; o >>= 1) acc += __shfl_xor(acc, o, 64);
  if (lane == 0) {
    float m = acc + b_ada[out];
    int grp = out >> 11, idx = out & 2047;
    mods[grp * 2048 + idx] = (grp & 1) ? tanhf(m) : (1.f + m);
  }
}

// ---------------- K1: h1 = rmsnorm(x)*w*(1+s_msa), f32 in -> bf16 out ------
__global__ __launch_bounds__(256) void ndt_norm_mod(
    const float* __restrict__ x, const float* __restrict__ w,
    const float* __restrict__ smod, bf16* __restrict__ out) {
  const int t = blockIdx.x, tid = threadIdx.x;
  __shared__ float red[4];
  float v[8];
  loadf8(x + (long)t * 2048 + tid * 8, v);
  float ss = 0.f;
  #pragma unroll
  for (int i = 0; i < 8; i++) ss += v[i] * v[i];
  #pragma unroll
  for (int o = 32; o; o >>= 1) ss += __shfl_xor(ss, o, 64);
  if ((tid & 63) == 0) red[tid >> 6] = ss;
  __syncthreads();
  float r = rsqrtf((red[0]+red[1]+red[2]+red[3]) * (1.f/2048.f) + 1e-5f);
  #pragma unroll
  for (int i = 0; i < 8; i++) {
    int cc = tid * 8 + i;
    out[(long)t * 2048 + cc] = f2bf(v[i] * r * w[cc] * smod[cc]);
  }
}

// ======= GEMM8: 256x256 tile, BK=64, 8 waves, 8-phase counted-vmcnt ========
// T1 XCD swizzle + T2 8-slot XOR swizzle (byte ^= ((row&7)<<4), same
// involution on inverse-swizzled stage SOURCE and ds_read addr) + T3/T4
// (8 phases / 2 K-tiles, vmcnt(6) at ph4/ph8 only) + T5 setprio +
// rule-#18 sched_barrier(0) pin at each phase's MFMA entry.
// SPLIT=1: grid.z = K-chunks, f32 partials: z even->C0+(z>>1)*MN, odd->C1+...
#define SWZ8(P) ((P) ^ ((((P) >> 7) & 7) << 4))

#define STG8(mat, q, t, tile) \
  g2lds16(src##mat[q] + (long)(t) * 128, (tile) + (q) * 8192 + (tid << 4))

#define READ_A8(tA, h) do { \
  _Pragma("unroll") for (int i_ = 0; i_ < 4; i_++) { \
    int row_ = wm * 128 + (h) * 64 + i_ * 16 + l15; \
    _Pragma("unroll") for (int kk_ = 0; kk_ < 2; kk_++) { \
      int P_ = row_ * 128 + kk_ * 64 + quad * 16; \
      af[kk_][i_] = *(const s8v*)((tA) + SWZ8(P_)); } } } while (0)

#define READ_B8(tB, nh, bfreg) do { \
  _Pragma("unroll") for (int j_ = 0; j_ < 2; j_++) { \
    int col_ = wn * 64 + (nh) * 32 + j_ * 16 + l15; \
    _Pragma("unroll") for (int kk_ = 0; kk_ < 2; kk_++) { \
      int P_ = col_ * 128 + kk_ * 64 + quad * 16; \
      bfreg[kk_][j_] = *(const s8v*)((tB) + SWZ8(P_)); } } } while (0)

#define PH_MMA(h, nh, bfreg) do { \
  asm volatile("" ::: "memory"); \
  __builtin_amdgcn_s_barrier(); \
  asm volatile("s_waitcnt lgkmcnt(0)" ::: "memory"); \
  __builtin_amdgcn_sched_barrier(0); \
  __builtin_amdgcn_s_setprio(1); \
  _Pragma("unroll") for (int i_ = 0; i_ < 4; i_++) \
    _Pragma("unroll") for (int j_ = 0; j_ < 2; j_++) { \
      acc[(h)*4 + i_][(nh)*2 + j_] = MFMA_BF16(af[0][i_], bfreg[0][j_], acc[(h)*4 + i_][(nh)*2 + j_]); \
      acc[(h)*4 + i_][(nh)*2 + j_] = MFMA_BF16(af[1][i_], bfreg[1][j_], acc[(h)*4 + i_][(nh)*2 + j_]); } \
  __builtin_amdgcn_s_setprio(0); \
  asm volatile("" ::: "memory"); \
  __builtin_amdgcn_s_barrier(); \
  asm volatile("" ::: "memory"); } while (0)

template<int EPI, int SPLIT>
__global__ __launch_bounds__(512, 2) void ndt_gemm8(
    const bf16* __restrict__ A, const bf16* __restrict__ B,
    void* __restrict__ C0, void* __restrict__ C1, const bf16* __restrict__ aux,
    int M, int N, int ldK, int Kc) {
  __shared__ alignas(16) short lds8[65536];   // 128 KiB: [A0|B0|A1|B1] 32KB each
  char* const tA0 = (char*)lds8;
  char* const tB0 = tA0 + 32768;
  char* const tA1 = tA0 + 65536;
  char* const tB1 = tA0 + 98304;

  const int tid = threadIdx.x;
  const int wid = tid >> 6, lane = tid & 63;
  const int quad = lane >> 4, l15 = lane & 15;
  const int wm = wid >> 2, wn = wid & 3;      // 2x4 wave grid, 128x64 per wave

  const int nbx = gridDim.x;
  int bid = blockIdx.y * nbx + blockIdx.x;
  const int nwg = nbx * (int)gridDim.y;
  if ((nwg & 7) == 0) bid = (bid & 7) * (nwg >> 3) + (bid >> 3);
  const long m0 = (long)(bid % nbx) * 256;
  const long n0 = (long)(bid / nbx) * 256;
  const long koff = (long)blockIdx.z * Kc;

  const int NT = Kc >> 6;
  const int NI = NT >> 1;

  const char* srcA[4];
  const char* srcB[4];
  #pragma unroll
  for (int q = 0; q < 4; q++) {
    int L = q * 8192 + (tid << 4);
    int Ls = SWZ8(L);
    srcA[q] = (const char*)(A + (m0 + (Ls >> 7)) * (long)ldK + koff) + (Ls & 127);
    srcB[q] = (const char*)(B + (n0 + (Ls >> 7)) * (long)ldK + koff) + (Ls & 127);
  }

  f32x4 acc[8][4];
  f32x4 zero4 = {0.f, 0.f, 0.f, 0.f};
  #pragma unroll
  for (int i = 0; i < 8; i++)
    #pragma unroll
    for (int j = 0; j < 4; j++) acc[i][j] = zero4;

  s8v af[2][4], bf0[2][2], bf1[2][2];

  // ---- prologue: tile0 full (8 loads), tile1 A full + B-h0 (6 loads) ----
  #pragma unroll
  for (int q = 0; q < 4; q++) STG8(A, q, 0, tA0);
  #pragma unroll
  for (int q = 0; q < 4; q++) STG8(B, q, 0, tB0);
  #pragma unroll
  for (int q = 0; q < 4; q++) STG8(A, q, 1, tA1);
  STG8(B, 0, 1, tB1);
  STG8(B, 1, 1, tB1);
  asm volatile("s_waitcnt vmcnt(6)" ::: "memory");
  asm volatile("" ::: "memory");
  __builtin_amdgcn_s_barrier();
  asm volatile("" ::: "memory");

  for (int it = 0; it < NI; ++it) {
    const int T = 2 * it;
    const int t2 = (T + 2 < NT) ? T + 2 : NT - 1;
    const int t3 = (T + 3 < NT) ? T + 3 : NT - 1;
    // ---- K-tile T (buf0) ----
    READ_A8(tA0, 0);
    READ_B8(tB0, 0, bf0);
    STG8(B, 2, T + 1, tB1);
    STG8(B, 3, T + 1, tB1);
    PH_MMA(0, 0, bf0);
    READ_B8(tB0, 1, bf1);
    STG8(A, 0, t2, tA0);
    STG8(A, 2, t2, tA0);
    PH_MMA(0, 1, bf1);
    READ_A8(tA0, 1);
    STG8(B, 0, t2, tB0);
    STG8(B, 1, t2, tB0);
    PH_MMA(1, 0, bf0);
    STG8(A, 1, t2, tA0);
    STG8(A, 3, t2, tA0);
    asm volatile("s_waitcnt vmcnt(6)" ::: "memory");
    PH_MMA(1, 1, bf1);
    // ---- K-tile T+1 (buf1) ----
    READ_A8(tA1, 0);
    READ_B8(tB1, 0, bf0);
    STG8(B, 2, t2, tB0);
    STG8(B, 3, t2, tB0);
    PH_MMA(0, 0, bf0);
    READ_B8(tB1, 1, bf1);
    STG8(A, 0, t3, tA1);
    STG8(A, 2, t3, tA1);
    PH_MMA(0, 1, bf1);
    READ_A8(tA1, 1);
    STG8(B, 0, t3, tB1);
    STG8(B, 1, t3, tB1);
    PH_MMA(1, 0, bf0);
    STG8(A, 1, t3, tA1);
    STG8(A, 3, t3, tA1);
    asm volatile("s_waitcnt vmcnt(6)" ::: "memory");
    PH_MMA(1, 1, bf1);
  }
  asm volatile("s_waitcnt vmcnt(0)" ::: "memory");

  if (SPLIT) {
    float* P = (float*)((blockIdx.z & 1) ? C1 : C0) +
               (long)(blockIdx.z >> 1) * ((long)M * N);
    #pragma unroll
    for (int mi = 0; mi < 8; mi++) {
      long rg = m0 + wm * 128 + mi * 16 + quad * 4;
      #pragma unroll
      for (int nj = 0; nj < 4; nj++) {
        long cg = n0 + wn * 64 + nj * 16 + l15;
        #pragma unroll
        for (int r = 0; r < 4; r++)
          P[(rg + r) * (long)N + cg] = acc[mi][nj][r];
      }
    }
  } else {
    bf16* Cb = (bf16*)C0;
    #pragma unroll
    for (int mi = 0; mi < 8; mi++) {
      long rg = m0 + wm * 128 + mi * 16 + quad * 4;
      #pragma unroll
      for (int nj = 0; nj < 4; nj++) {
        long cg = n0 + wn * 64 + nj * 16 + l15;
        #pragma unroll
        for (int r = 0; r < 4; r++) {
          float v = acc[mi][nj][r];
          long idx = (rg + r) * (long)N + cg;
          if (EPI == 1) v = v / (1.f + __expf(-v));
          if (EPI == 2) v = v * bf2f(aux[idx]);
          Cb[idx] = f2bf(v);
        }
      }
    }
  }
}

// ------- GEMM (fallback): B is f32, converted during explicit staging ------
template<int EPI>
__global__ __launch_bounds__(256) void ndt_gemm_bt(
    const bf16* __restrict__ A, const float* __restrict__ B,
    bf16* __restrict__ C, const bf16* __restrict__ aux,
    int M, int N, int K) {
  __shared__ alignas(16) short sA[128 * 32];
  __shared__ alignas(16) short sB[128 * 32];
  const int tid = threadIdx.x;
  const int wave = tid >> 6, lane = tid & 63;
  const int quad = lane >> 4, l15 = lane & 15;
  const int wm = (wave >> 1) << 6, wn = (wave & 1) << 6;
  const long m0 = (long)blockIdx.x * 128, n0 = (long)blockIdx.y * 128;
  f32x4 zero4 = {0.f, 0.f, 0.f, 0.f};
  f32x4 acc[4][4];
  #pragma unroll
  for (int i = 0; i < 4; i++)
    #pragma unroll
    for (int j = 0; j < 4; j++) acc[i][j] = zero4;
  const int srow = lane >> 2;
  const int skc  = (lane & 3) * 8;
  const int r0 = (wave * 2) * 16 + srow;
  const int r1 = (wave * 2 + 1) * 16 + srow;
  const bf16*  pa0 = A + (m0 + r0) * (long)K + skc;
  const bf16*  pa1 = A + (m0 + r1) * (long)K + skc;
  const float* pb0 = B + (n0 + r0) * (long)K + skc;
  const float* pb1 = B + (n0 + r1) * (long)K + skc;
  uint4* da0 = (uint4*)&sA[r0 * 32 + skc];
  uint4* da1 = (uint4*)&sA[r1 * 32 + skc];
  s8v* db0 = (s8v*)&sB[r0 * 32 + skc];
  s8v* db1 = (s8v*)&sB[r1 * 32 + skc];
  for (int k0 = 0; k0 < K; k0 += 32) {
    uint4 va0 = *(const uint4*)pa0; pa0 += 32;
    uint4 va1 = *(const uint4*)pa1; pa1 += 32;
    s8v vb0 = cvt8(pb0); pb0 += 32;
    s8v vb1 = cvt8(pb1); pb1 += 32;
    *da0 = va0; *da1 = va1; *db0 = vb0; *db1 = vb1;
    __syncthreads();
    s8v af[4], bfr[4];
    #pragma unroll
    for (int i = 0; i < 4; i++) af[i]  = *(const s8v*)&sA[(wm + i*16 + l15)*32 + quad*8];
    #pragma unroll
    for (int j = 0; j < 4; j++) bfr[j] = *(const s8v*)&sB[(wn + j*16 + l15)*32 + quad*8];
    #pragma unroll
    for (int i = 0; i < 4; i++)
      #pragma unroll
      for (int j = 0; j < 4; j++)
        acc[i][j] = MFMA_BF16(af[i], bfr[j], acc[i][j]);
    __syncthreads();
  }
  #pragma unroll
  for (int i = 0; i < 4; i++) {
    long rg = m0 + wm + i*16 + quad*4;
    #pragma unroll
    for (int j = 0; j < 4; j++) {
      long cg = n0 + wn + j*16 + l15;
      #pragma unroll
      for (int r = 0; r < 4; r++) {
        float v = acc[i][j][r];
        long idx = (rg + r) * (long)N + cg;
        if (EPI == 1) v = v / (1.f + __expf(-v));
        if (EPI == 2) v = v * bf2f(aux[idx]);
        C[idx] = f2bf(v);
      }
    }
  }
}

// ---------------- K3: q/k rmsnorm + RoPE, v copy (fallback, bf16 in) -------
__global__ __launch_bounds__(256) void ndt_qkrope(
    const bf16* __restrict__ qkv, const float* __restrict__ qw, const float* __restrict__ kw,
    const float* __restrict__ fc, const float* __restrict__ fs,
    bf16* __restrict__ qb, bf16* __restrict__ kb, bf16* __restrict__ vb) {
  const int wid = blockIdx.x * 4 + (threadIdx.x >> 6);
  const int lane = threadIdx.x & 63;
  const int t = wid / 48;
  const int u = wid - t * 48;
  if (u < 40) {
    const bool isq = (u < 32);
    const int hh = isq ? u : (u - 32);
    const long src = (long)t * 3072 + (isq ? hh * 64 : 2048 + hh * 64) + lane;
    float v = bf2f(qkv[src]);
    float ss = v * v;
    #pragma unroll
    for (int o = 32; o; o >>= 1) ss += __shfl_xor(ss, o, 64);
    float r = rsqrtf(ss * (1.f/64.f) + 1e-5f);
    float y = v * r * (isq ? qw[lane] : kw[lane]);
    int j = lane >> 1;
    float cv = fc[t * 32 + j];
    float sv = fs[t * 32 + j];
    float p = __shfl_xor(y, 1, 64);
    float out = (lane & 1) ? (p * sv + y * cv) : (y * cv - p * sv);
    if (isq) qb[(long)t * 2048 + hh * 64 + lane] = f2bf(out);
    else     kb[(long)t * 512 + hh * 64 + lane] = f2bf(out);
  } else {
    const int vh = u - 40;
    vb[(long)t * 512 + vh * 64 + lane] = qkv[(long)t * 3072 + 2560 + vh * 64 + lane];
  }
}

// ------ K3p: same, qkv = p0+p1 (f32 split-K partials, fast path) -----------
__global__ __launch_bounds__(256) void ndt_qkropep(
    const float* __restrict__ p0, const float* __restrict__ p1,
    const float* __restrict__ qw, const float* __restrict__ kw,
    const float* __restrict__ fc, const float* __restrict__ fs,
    bf16* __restrict__ qb, bf16* __restrict__ kb, bf16* __restrict__ vb) {
  const int wid = blockIdx.x * 4 + (threadIdx.x >> 6);
  const int lane = threadIdx.x & 63;
  const int t = wid / 48;
  const int u = wid - t * 48;
  if (u < 40) {
    const bool isq = (u < 32);
    const int hh = isq ? u : (u - 32);
    const long src = (long)t * 3072 + (isq ? hh * 64 : 2048 + hh * 64) + lane;
    float v = p0[src] + p1[src];
    float ss = v * v;
    #pragma unroll
    for (int o = 32; o; o >>= 1) ss += __shfl_xor(ss, o, 64);
    float r = rsqrtf(ss * (1.f/64.f) + 1e-5f);
    float y = v * r * (isq ? qw[lane] : kw[lane]);
    int j = lane >> 1;
    float cv = fc[t * 32 + j];
    float sv = fs[t * 32 + j];
    float p = __shfl_xor(y, 1, 64);
    float out = (lane & 1) ? (p * sv + y * cv) : (y * cv - p * sv);
    if (isq) qb[(long)t * 2048 + hh * 64 + lane] = f2bf(out);
    else     kb[(long)t * 512 + hh * 64 + lane] = f2bf(out);
  } else {
    const int vh = u - 40;
    const long vsrc = (long)t * 3072 + 2560 + vh * 64 + lane;
    vb[(long)t * 512 + vh * 64 + lane] = f2bf(p0[vsrc] + p1[vsrc]);
  }
}

// ---------------- K4: flash attention (GQA 32 q-heads / 8 kv-heads) --------
__global__ __launch_bounds__(256) void ndt_attn(
    const bf16* __restrict__ qb, const bf16* __restrict__ kb,
    const bf16* __restrict__ vb, bf16* __restrict__ ob) {
  const int h = blockIdx.y;
  const int qblk = blockIdx.x;
  const int tid = threadIdx.x;
  const int wave = tid >> 6, lane = tid & 63;
  const int quad = lane >> 4, l15 = lane & 15;
  const int kh = h >> 2;
  __shared__ alignas(16) short kT[64 * 72];
  __shared__ alignas(16) short vT[64 * 72];
  __shared__ alignas(16) short pT[4][16 * 72];
  const int qrow = qblk * 64 + wave * 16 + l15;
  const short* qptr = (const short*)qb + (long)qrow * 2048 + h * 64;
  s8v qf0 = *(const s8v*)(qptr + quad * 8);
  s8v qf1 = *(const s8v*)(qptr + 32 + quad * 8);
  f32x4 zero4 = {0.f, 0.f, 0.f, 0.f};
  f32x4 o[4];
  float mr[4], lr[4];
  #pragma unroll
  for (int r = 0; r < 4; r++) { o[r] = zero4; mr[r] = -1e30f; lr[r] = 0.f; }
  const int skey = tid >> 2;
  const int sdg = (tid & 3) * 16;
  for (int kt = 0; kt < 32; kt++) {
    {
      const short* ksrc = (const short*)kb + ((long)(kt * 64 + skey) * 8 + kh) * 64 + sdg;
      *(uint4*)&kT[skey * 72 + sdg]     = *(const uint4*)(ksrc);
      *(uint4*)&kT[skey * 72 + sdg + 8] = *(const uint4*)(ksrc + 8);
      const short* vsrc = (const short*)vb + ((long)(kt * 64 + skey) * 8 + kh) * 64 + sdg;
      short tv[16];
      *(uint4*)&tv[0] = *(const uint4*)(vsrc);
      *(uint4*)&tv[8] = *(const uint4*)(vsrc + 8);
      #pragma unroll
      for (int i = 0; i < 16; i++) vT[(sdg + i) * 72 + skey] = tv[i];
    }
    __syncthreads();
    f32x4 s[4];
    #pragma unroll
    for (int b4 = 0; b4 < 4; b4++) {
      const short* kr = &kT[(b4 * 16 + l15) * 72];
      s8v kf0 = *(const s8v*)(kr + quad * 8);
      s8v kf1 = *(const s8v*)(kr + 32 + quad * 8);
      f32x4 z = zero4;
      z = MFMA_BF16(qf0, kf0, z);
      z = MFMA_BF16(qf1, kf1, z);
      s[b4] = z;
    }
    #pragma unroll
    for (int r = 0; r < 4; r++) {
      float mx = -1e30f;
      #pragma unroll
      for (int b4 = 0; b4 < 4; b4++) { float sv2 = s[b4][r] * 0.125f; s[b4][r] = sv2; mx = fmaxf(mx, sv2); }
      mx = fmaxf(mx, __shfl_xor(mx, 1, 64));
      mx = fmaxf(mx, __shfl_xor(mx, 2, 64));
      mx = fmaxf(mx, __shfl_xor(mx, 4, 64));
      mx = fmaxf(mx, __shfl_xor(mx, 8, 64));
      float nm = fmaxf(mr[r], mx);
      float alpha = __expf(mr[r] - nm);
      mr[r] = nm;
      float rs = 0.f;
      #pragma unroll
      for (int b4 = 0; b4 < 4; b4++) { float p = __expf(s[b4][r] - nm); s[b4][r] = p; rs += p; }
      rs += __shfl_xor(rs, 1, 64);
      rs += __shfl_xor(rs, 2, 64);
      rs += __shfl_xor(rs, 4, 64);
      rs += __shfl_xor(rs, 8, 64);
      lr[r] = lr[r] * alpha + rs;
      #pragma unroll
      for (int cb = 0; cb < 4; cb++) o[cb][r] *= alpha;
    }
    short* pw = &pT[wave][0];
    #pragma unroll
    for (int b4 = 0; b4 < 4; b4++)
      #pragma unroll
      for (int r = 0; r < 4; r++)
        pw[(quad * 4 + r) * 72 + b4 * 16 + l15] = f2bfbits(s[b4][r]);
    const short* pr = &pT[wave][0];
    s8v pf0 = *(const s8v*)(pr + l15 * 72 + quad * 8);
    s8v pf1 = *(const s8v*)(pr + l15 * 72 + 32 + quad * 8);
    #pragma unroll
    for (int cb = 0; cb < 4; cb++) {
      const short* vr = &vT[(cb * 16 + l15) * 72];
      s8v vf0 = *(const s8v*)(vr + quad * 8);
      s8v vf1 = *(const s8v*)(vr + 32 + quad * 8);
      o[cb] = MFMA_BF16(pf0, vf0, o[cb]);
      o[cb] = MFMA_BF16(pf1, vf1, o[cb]);
    }
    __syncthreads();
  }
  #pragma unroll
  for (int cb = 0; cb < 4; cb++)
    #pragma unroll
    for (int r = 0; r < 4; r++) {
      int tok = qblk * 64 + wave * 16 + quad * 4 + r;
      ob[(long)tok * 2048 + h * 64 + cb * 16 + l15] = f2bf(o[cb][r] / lr[r]);
    }
}

// ---- K6 fallback: ao is bf16 ----------------------------------------------
__global__ __launch_bounds__(256) void ndt_resid1(
    const float* __restrict__ x, const bf16* __restrict__ ao,
    const float* __restrict__ mods, const float* __restrict__ w_n2,
    const float* __restrict__ w_f1, float* __restrict__ x1, bf16* __restrict__ h2) {
  const int t = blockIdx.x, tid = threadIdx.x;
  __shared__ float red1[4], red2[4];
  const long base = (long)t * 2048;
  float a[8], xv[8], y[8];
  load8(ao + base + tid * 8, a);
  loadf8(x + base + tid * 8, xv);
  float ss = 0.f;
  #pragma unroll
  for (int i = 0; i < 8; i++) ss += a[i] * a[i];
  #pragma unroll
  for (int o = 32; o; o >>= 1) ss += __shfl_xor(ss, o, 64);
  if ((tid & 63) == 0) red1[tid >> 6] = ss;
  __syncthreads();
  float r1 = rsqrtf((red1[0]+red1[1]+red1[2]+red1[3]) * (1.f/2048.f) + 1e-5f);
  float ss2 = 0.f;
  #pragma unroll
  for (int i = 0; i < 8; i++) {
    int cc = tid * 8 + i;
    float yy = xv[i] + mods[2048 + cc] * (a[i] * r1 * w_n2[cc]);
    y[i] = yy; ss2 += yy * yy;
    x1[base + cc] = yy;
  }
  #pragma unroll
  for (int o = 32; o; o >>= 1) ss2 += __shfl_xor(ss2, o, 64);
  if ((tid & 63) == 0) red2[tid >> 6] = ss2;
  __syncthreads();
  float r2 = rsqrtf((red2[0]+red2[1]+red2[2]+red2[3]) * (1.f/2048.f) + 1e-5f);
  #pragma unroll
  for (int i = 0; i < 8; i++) {
    int cc = tid * 8 + i;
    h2[base + cc] = f2bf(y[i] * r2 * w_f1[cc] * mods[4096 + cc]);
  }
}

// ---- K6 fast: ao = pA + pA[MN] + pB + pB[MN] (f32 split-K partials) -------
__global__ __launch_bounds__(256) void ndt_resid1p(
    const float* __restrict__ x, const float* __restrict__ pA,
    const float* __restrict__ pB,
    const float* __restrict__ mods, const float* __restrict__ w_n2,
    const float* __restrict__ w_f1, float* __restrict__ x1, bf16* __restrict__ h2) {
  const int t = blockIdx.x, tid = threadIdx.x;
  const long MN = 4194304;
  __shared__ float red1[4], red2[4];
  const long base = (long)t * 2048;
  float a[8], tmp[8], xv[8], y[8];
  loadf8(pA + base + tid * 8, a);
  loadf8(pA + MN + base + tid * 8, tmp);
  #pragma unroll
  for (int i = 0; i < 8; i++) a[i] += tmp[i];
  loadf8(pB + base + tid * 8, tmp);
  #pragma unroll
  for (int i = 0; i < 8; i++) a[i] += tmp[i];
  loadf8(pB + MN + base + tid * 8, tmp);
  #pragma unroll
  for (int i = 0; i < 8; i++) a[i] += tmp[i];
  loadf8(x + base + tid * 8, xv);
  float ss = 0.f;
  #pragma unroll
  for (int i = 0; i < 8; i++) ss += a[i] * a[i];
  #pragma unroll
  for (int o = 32; o; o >>= 1) ss += __shfl_xor(ss, o, 64);
  if ((tid & 63) == 0) red1[tid >> 6] = ss;
  __syncthreads();
  float r1 = rsqrtf((red1[0]+red1[1]+red1[2]+red1[3]) * (1.f/2048.f) + 1e-5f);
  float ss2 = 0.f;
  #pragma unroll
  for (int i = 0; i < 8; i++) {
    int cc = tid * 8 + i;
    float yy = xv[i] + mods[2048 + cc] * (a[i] * r1 * w_n2[cc]);
    y[i] = yy; ss2 += yy * yy;
    x1[base + cc] = yy;
  }
  #pragma unroll
  for (int o = 32; o; o >>= 1) ss2 += __shfl_xor(ss2, o, 64);
  if ((tid & 63) == 0) red2[tid >> 6] = ss2;
  __syncthreads();
  float r2 = rsqrtf((red2[0]+red2[1]+red2[2]+red2[3]) * (1.f/2048.f) + 1e-5f);
  #pragma unroll
  for (int i = 0; i < 8; i++) {
    int cc = tid * 8 + i;
    h2[base + cc] = f2bf(y[i] * r2 * w_f1[cc] * mods[4096 + cc]);
  }
}

// ---- K10 fallback: ffn is bf16 --------------------------------------------
__global__ __launch_bounds__(256) void ndt_resid2(
    const float* __restrict__ x1, const bf16* __restrict__ ffn,
    const float* __restrict__ mods, const float* __restrict__ w_f2,
    float* __restrict__ out) {
  const int t = blockIdx.x, tid = threadIdx.x;
  __shared__ float red[4];
  const long base = (long)t * 2048;
  float f[8], xv[8];
  load8(ffn + base + tid * 8, f);
  loadf8(x1 + base + tid * 8, xv);
  float ss = 0.f;
  #pragma unroll
  for (int i = 0; i < 8; i++) ss += f[i] * f[i];
  #pragma unroll
  for (int o = 32; o; o >>= 1) ss += __shfl_xor(ss, o, 64);
  if ((tid & 63) == 0) red[tid >> 6] = ss;
  __syncthreads();
  float r = rsqrtf((red[0]+red[1]+red[2]+red[3]) * (1.f/2048.f) + 1e-5f);
  #pragma unroll
  for (int i = 0; i < 8; i++) {
    int cc = tid * 8 + i;
    out[base + cc] = xv[i] + mods[6144 + cc] * (f[i] * r * w_f2[cc]);
  }
}

// ---- K10 fast: ffn = pA + pA[MN] + pB + pB[MN] ----------------------------
__global__ __launch_bounds__(256) void ndt_resid2p(
    const float* __restrict__ x1, const float* __restrict__ pA,
    const float* __restrict__ pB,
    const float* __restrict__ mods, const float* __restrict__ w_f2,
    float* __restrict__ out) {
  const int t = blockIdx.x, tid = threadIdx.x;
  const long MN = 4194304;
  __shared__ float red[4];
  const long base = (long)t * 2048;
  float f[8], tmp[8], xv[8];
  loadf8(pA + base + tid * 8, f);
  loadf8(pA + MN + base + tid * 8, tmp);
  #pragma unroll
  for (int i = 0; i < 8; i++) f[i] += tmp[i];
  loadf8(pB + base + tid * 8, tmp);
  #pragma unroll
  for (int i = 0; i < 8; i++) f[i] += tmp[i];
  loadf8(pB + MN + base + tid * 8, tmp);
  #pragma unroll
  for (int i = 0; i < 8; i++) f[i] += tmp[i];
  loadf8(x1 + base + tid * 8, xv);
  float ss = 0.f;
  #pragma unroll
  for (int i = 0; i < 8; i++) ss += f[i] * f[i];
  #pragma unroll
  for (int o = 32; o; o >>= 1) ss += __shfl_xor(ss, o, 64);
  if ((tid & 63) == 0) red[tid >> 6] = ss;
  __syncthreads();
  float r = rsqrtf((red[0]+red[1]+red[2]+red[3]) * (1.f/2048.f) + 1e-5f);
  #pragma unroll
  for (int i = 0; i < 8; i++) {
    int cc = tid * 8 + i;
    out[base + cc] = xv[i] + mods[6144 + cc] * (f[i] * r * w_f2[cc]);
  }
}

// ---------------------------------------------------------------------------
extern "C" void kernel_launch(void* const* d_in, const int* in_sizes, int n_in,
                              void* d_out, int out_size, void* d_ws, size_t ws_size,
                              hipStream_t stream) {
  const float* x     = (const float*)d_in[0];
  const float* fc    = (const float*)d_in[2];
  const float* fs    = (const float*)d_in[3];
  const float* c     = (const float*)d_in[4];
  const float* w_qkv = (const float*)d_in[5];
  const float* w_out = (const float*)d_in[6];
  const float* q_nw  = (const float*)d_in[7];
  const float* k_nw  = (const float*)d_in[8];
  const float* an1   = (const float*)d_in[9];
  const float* an2   = (const float*)d_in[10];
  const float* fn1   = (const float*)d_in[11];
  const float* fn2   = (const float*)d_in[12];
  const float* w1    = (const float*)d_in[13];
  const float* w2    = (const float*)d_in[14];
  const float* w3    = (const float*)d_in[15];
  const float* w_ada = (const float*)d_in[16];
  const float* b_ada = (const float*)d_in[17];
  float* out = (float*)d_out;

  const size_t MB = 1024 * 1024;
  char* w = (char*)d_ws;
  float* mods = (float*)(w);                    // 32 KB f32
  char* base = w + 32768;
  // fast-path region lifetime map:
  //  0..8    h1: qkv-A input -> attn output; later free -> w2 partials (z0,z2 @ 0..32)
  //  8..20   qkv (fallback only) / free
  // 20..28   qb -> h2
  // 28..32   kb, vb
  // 32..48   x1 (f32, alive resid1->resid2)
  // 48..80   t1f: qkv partials (z0: 24MB) -> attn-out partials (z0,z2) -> t1 bf16
  // 80..112  Wa weights (w_qkv -> w_out -> w1 -> w2)
  // 112..144 Wb: qkv partial z1 -> attn-out partials (z1,z3) -> w3 -> w2 partials (z1,z3)
  bf16* h1   = (bf16*)(base);
  bf16* attn = h1;
  bf16* ffn  = h1;
  bf16* qkv  = (bf16*)(base + 8 * MB);
  bf16* ao   = qkv;
  bf16* qb   = (bf16*)(base + 20 * MB);
  bf16* h2   = qb;
  bf16* kb   = (bf16*)(base + 28 * MB);
  bf16* vb   = (bf16*)(base + 30 * MB);
  float* x1  = (float*)(base + 32 * MB);
  bf16* t1   = (bf16*)(base + 48 * MB);
  bf16* Wa   = (bf16*)(base + 80 * MB);
  bf16* Wb   = (bf16*)(base + 112 * MB);
  float* t1f = (float*)t1;
  float* wbf = (float*)Wb;
  float* p0f = (float*)base;
  const size_t needed = 32768 + 144 * MB;

  ndt_ada<<<2048, 256, 0, stream>>>(c, w_ada, b_ada, mods);
  ndt_norm_mod<<<2048, 256, 0, stream>>>(x, an1, mods, h1);

  if (ws_size >= needed) {
    // qkv: M=2048 N=3072 K=2048, split-2 (8x12x2 = 192 blocks)
    ndt_cvt<<<3072, 256, 0, stream>>>(w_qkv, Wa, 6291456L);
    ndt_gemm8<0,1><<<dim3(8, 12, 2), 512, 0, stream>>>(h1, Wa, t1f, wbf, nullptr, 2048, 3072, 2048, 1024);
    ndt_qkropep<<<24576, 256, 0, stream>>>(t1f, wbf, q_nw, k_nw, fc, fs, qb, kb, vb);
    ndt_attn<<<dim3(32, 32), 256, 0, stream>>>(qb, kb, vb, attn);
    // attn-out: 2048^3, split-4 (8x8x4 = 256 blocks)
    ndt_cvt<<<2048, 256, 0, stream>>>(w_out, Wa, 4194304L);
    ndt_gemm8<0,1><<<dim3(8, 8, 4), 512, 0, stream>>>(attn, Wa, t1f, wbf, nullptr, 2048, 2048, 2048, 512);
    ndt_resid1p<<<2048, 256, 0, stream>>>(x, t1f, wbf, mods, an2, fn1, x1, h2);
    // FFN up: M=2048 N=8192 K=2048, full-K (8x32 = 256 blocks)
    ndt_cvt<<<8192, 256, 0, stream>>>(w1, Wa, 16777216L);
    ndt_cvt<<<8192, 256, 0, stream>>>(w3, Wb, 16777216L);
    ndt_gemm8<1,0><<<dim3(8, 32, 1), 512, 0, stream>>>(h2, Wa, t1, nullptr, nullptr, 2048, 8192, 2048, 2048);
    ndt_gemm8<2,0><<<dim3(8, 32, 1), 512, 0, stream>>>(h2, Wb, t1, nullptr, t1, 2048, 8192, 2048, 2048);
    // w2 down: M=N=2048 K=8192, split-4 (8x8x4 = 256 blocks)
    ndt_cvt<<<8192, 256, 0, stream>>>(w2, Wa, 16777216L);
    ndt_gemm8<0,1><<<dim3(8, 8, 4), 512, 0, stream>>>(t1, Wa, p0f, wbf, nullptr, 2048, 2048, 8192, 2048);
    ndt_resid2p<<<2048, 256, 0, stream>>>(x1, p0f, wbf, mods, fn2, out);
  } else {
    // --- fallback: round-3 passing path (f32 B staged with in-loop cvt) ---
    ndt_gemm_bt<0><<<dim3(16, 24), 256, 0, stream>>>(h1, w_qkv, qkv, nullptr, 2048, 3072, 2048);
    ndt_qkrope<<<24576, 256, 0, stream>>>(qkv, q_nw, k_nw, fc, fs, qb, kb, vb);
    ndt_attn<<<dim3(32, 32), 256, 0, stream>>>(qb, kb, vb, attn);
    ndt_gemm_bt<0><<<dim3(16, 16), 256, 0, stream>>>(attn, w_out, ao, nullptr, 2048, 2048, 2048);
    ndt_resid1<<<2048, 256, 0, stream>>>(x, ao, mods, an2, fn1, x1, h2);
    ndt_gemm_bt<1><<<dim3(16, 64), 256, 0, stream>>>(h2, w1, t1, nullptr, 2048, 8192, 2048);
    ndt_gemm_bt<2><<<dim3(16, 64), 256, 0, stream>>>(h2, w3, t1, t1, 2048, 8192, 2048);
    ndt_gemm_bt<0><<<dim3(16, 16), 256, 0, stream>>>(t1, w2, ffn, nullptr, 2048, 2048, 8192);
    ndt_resid2<<<2048, 256, 0, stream>>>(x1, ffn, mods, fn2, out);
  }
}